// Round 1
// baseline (1864.080 us; speedup 1.0000x reference)
//
#include <hip/hip_runtime.h>
#include <math.h>

typedef unsigned short u16;
typedef __attribute__((ext_vector_type(4))) float f32x4;
typedef __attribute__((ext_vector_type(8))) short bf16x8;
typedef __attribute__((ext_vector_type(8))) unsigned short u16x8;

#define B_ROWS 8192
#define GLDS(gaddr, laddr)                                                                  \
  __builtin_amdgcn_global_load_lds(                                                        \
      (const __attribute__((address_space(1))) unsigned int*)(const void*)(gaddr),          \
      (__attribute__((address_space(3))) unsigned int*)(void*)(laddr), 16, 0, 0)

__device__ __forceinline__ u16 f2bf(float f) {
  unsigned int u = __float_as_uint(f);
  unsigned int r = u + 0x7fffu + ((u >> 16) & 1u);
  return (u16)(r >> 16);
}

// ---------------- block-wide (256 thr) dual reduction ----------------
__device__ __forceinline__ void block_reduce2(float& a, float& b) {
  __shared__ float sb[8];
  #pragma unroll
  for (int off = 32; off > 0; off >>= 1) {
    a += __shfl_down(a, off, 64);
    b += __shfl_down(b, off, 64);
  }
  int lane = threadIdx.x & 63, wid = threadIdx.x >> 6;
  if (lane == 0) { sb[wid] = a; sb[wid + 4] = b; }
  __syncthreads();
  a = sb[0] + sb[1] + sb[2] + sb[3];
  b = sb[4] + sb[5] + sb[6] + sb[7];
  __syncthreads();
}

// ---------------- LayerNorm (2048 cols) -> bf16 ----------------
__global__ __launch_bounds__(256) void ln_kernel(const float* __restrict__ seq,
                                                 const float* __restrict__ w,
                                                 const float* __restrict__ b,
                                                 u16* __restrict__ xbf) {
  int row = blockIdx.x, t = threadIdx.x;
  const f32x4* x = (const f32x4*)(seq + (size_t)row * 2048);
  f32x4 v0 = x[2 * t], v1 = x[2 * t + 1];
  float s = 0.f, q = 0.f;
  #pragma unroll
  for (int i = 0; i < 4; ++i) { s += v0[i] + v1[i]; q += v0[i] * v0[i] + v1[i] * v1[i]; }
  block_reduce2(s, q);
  float mu = s * (1.f / 2048.f);
  float var = q * (1.f / 2048.f) - mu * mu;
  float rstd = rsqrtf(var + 1e-5f);
  f32x4 w0 = ((const f32x4*)w)[2 * t], w1 = ((const f32x4*)w)[2 * t + 1];
  f32x4 b0 = ((const f32x4*)b)[2 * t], b1 = ((const f32x4*)b)[2 * t + 1];
  u16x8 o;
  #pragma unroll
  for (int i = 0; i < 4; ++i) o[i] = f2bf((v0[i] - mu) * rstd * w0[i] + b0[i]);
  #pragma unroll
  for (int i = 0; i < 4; ++i) o[4 + i] = f2bf((v1[i] - mu) * rstd * w1[i] + b1[i]);
  ((u16x8*)(xbf + (size_t)row * 2048))[t] = o;
}

// ---------------- fp32 -> bf16 elementwise ----------------
__global__ __launch_bounds__(256) void cvt_bf16(const float* __restrict__ in,
                                                u16* __restrict__ out, int n) {
  int i = blockIdx.x * 256 + threadIdx.x;
  int stride = gridDim.x * 256;
  for (; i < n; i += stride) out[i] = f2bf(in[i]);
}

// ---------------- transpose + cvt: out[c][r] = bf16(in[r][c]) ----------------
__global__ void transpose_cvt(const float* __restrict__ in, long ibstride, int R, int Cc,
                              u16* __restrict__ out, long obstride, int ldo) {
  in += (size_t)blockIdx.z * ibstride;
  out += (size_t)blockIdx.z * obstride;
  __shared__ float tile[32][33];
  int c0 = blockIdx.x * 32, r0 = blockIdx.y * 32;
  int tx = threadIdx.x, ty = threadIdx.y;
  #pragma unroll
  for (int j = 0; j < 4; ++j) {
    int rr = r0 + ty + j * 8;
    if (rr < R && c0 + tx < Cc) tile[ty + j * 8][tx] = in[(size_t)rr * Cc + c0 + tx];
  }
  __syncthreads();
  #pragma unroll
  for (int j = 0; j < 4; ++j) {
    int cc = c0 + ty + j * 8, rr = r0 + tx;
    if (cc < Cc && rr < R) out[(size_t)cc * ldo + rr] = f2bf(tile[tx][ty + j * 8]);
  }
}

// ---------------- bias packing ----------------
__global__ __launch_bounds__(256) void pack_bias(const float* __restrict__ bi, const float* __restrict__ bf_,
                                                 const float* __restrict__ bz, const float* __restrict__ bo,
                                                 const float* __restrict__ bup,
                                                 float* __restrict__ biasg, float* __restrict__ biasup) {
  int i = blockIdx.x * 256 + threadIdx.x;
  if (i < 8192) {
    int g = i >> 11, j = i & 2047;
    const float* p = (g == 0) ? bi : (g == 1) ? bf_ : (g == 2) ? bz : bo;
    biasg[i] = p[j];
  }
  if (i < 5504) biasup[i] = (i < 5460) ? bup[i] : 0.f;
}

// ---------------- MFMA GEMM, A[M][K] x Bt[N][K] -> C fp32, m97 structure ----------------
__device__ __forceinline__ void compute_step(const u16* lA, const u16* lB, int wm, int wn,
                                             int r, int sgrp, f32x4 (&acc)[4][4]) {
  #pragma unroll
  for (int ks = 0; ks < 2; ++ks) {
    bf16x8 af[4], bb[4];
    #pragma unroll
    for (int mi = 0; mi < 4; ++mi)
      af[mi] = *(const bf16x8*)(lA + ((wm * 64 + mi * 16 + r) * 64 + ks * 32 + sgrp * 8));
    #pragma unroll
    for (int ni = 0; ni < 4; ++ni)
      bb[ni] = *(const bf16x8*)(lB + ((wn * 64 + ni * 16 + r) * 64 + ks * 32 + sgrp * 8));
    #pragma unroll
    for (int mi = 0; mi < 4; ++mi)
      #pragma unroll
      for (int ni = 0; ni < 4; ++ni)
        acc[mi][ni] = __builtin_amdgcn_mfma_f32_16x16x32_bf16(af[mi], bb[ni], acc[mi][ni], 0, 0, 0);
  }
}

__global__ __launch_bounds__(256) void gemm_bt(
    const u16* __restrict__ A, int lda,
    const u16* __restrict__ Bt, int ldb, int K,
    float* __restrict__ C, int ldc, int Nvalid, int ntN,
    const float* __restrict__ bias,
    const float* __restrict__ addsrc, int ldadd,
    const u16* __restrict__ hbf, const u16* __restrict__ RTw, int rec) {
  __shared__ char smem[32768];
  u16* lA = (u16*)smem;
  u16* lB = (u16*)(smem + 16384);
  int bid = blockIdx.x;
  int m0 = (bid / ntN) * 128, n0 = (bid % ntN) * 128;
  int t = threadIdx.x, lane = t & 63, wave = t >> 6;
  int wm = wave >> 1, wn = wave & 1;
  int r = lane & 15, sgrp = lane >> 4;
  int crow = lane >> 3;            // staging: row within 8-row chunk
  int ccol = (lane & 7) * 8;       // staging: bf16 col offset

  f32x4 acc[4][4] = {};

  const u16* Abase = A + (size_t)m0 * lda;
  const u16* Bbase = Bt + (size_t)n0 * ldb;

  for (int k0 = 0; k0 < K; k0 += 64) {
    __syncthreads();
    #pragma unroll
    for (int i = 0; i < 4; ++i) {
      int chunk = wave * 4 + i;
      GLDS(Abase + (size_t)(chunk * 8 + crow) * lda + k0 + ccol, smem + chunk * 1024);
      GLDS(Bbase + (size_t)(chunk * 8 + crow) * ldb + k0 + ccol, smem + 16384 + chunk * 1024);
    }
    __syncthreads();
    compute_step(lA, lB, wm, wn, r, sgrp, acc);
  }

  if (rec) {  // block-diagonal recurrent phase: += h[:, head*256:+256] @ R_g[head]
    int g = n0 >> 11, nn = n0 & 2047, head = nn >> 8, e0 = nn & 255;
    const u16* A2 = hbf + head * 256;
    const u16* B2 = RTw + (size_t)((g * 8 + head) * 256 + e0) * 256;
    for (int k0 = 0; k0 < 256; k0 += 64) {
      __syncthreads();
      #pragma unroll
      for (int i = 0; i < 4; ++i) {
        int chunk = wave * 4 + i;
        GLDS(A2 + (size_t)(m0 + chunk * 8 + crow) * 2048 + k0 + ccol, smem + chunk * 1024);
        GLDS(B2 + (size_t)(chunk * 8 + crow) * 256 + k0 + ccol, smem + 16384 + chunk * 1024);
      }
      __syncthreads();
      compute_step(lA, lB, wm, wn, r, sgrp, acc);
    }
  }

  #pragma unroll
  for (int ni = 0; ni < 4; ++ni) {
    int col = n0 + wn * 64 + ni * 16 + r;
    if (col >= Nvalid) continue;
    float bv = bias ? bias[col] : 0.f;
    #pragma unroll
    for (int mi = 0; mi < 4; ++mi) {
      int row = m0 + wm * 64 + mi * 16 + sgrp * 4;
      #pragma unroll
      for (int jj = 0; jj < 4; ++jj) {
        float v = acc[mi][ni][jj] + bv;
        if (addsrc) v += addsrc[(size_t)(row + jj) * ldadd + col];
        C[(size_t)(row + jj) * ldc + col] = v;
      }
    }
  }
}

// ---------------- sLSTM pointwise + GroupNorm (block = one (row, head)) ----------------
__global__ __launch_bounds__(256) void pointwise_gn(
    const float* __restrict__ G, const float* __restrict__ c1, const float* __restrict__ n1,
    const float* __restrict__ m1, const float* __restrict__ gnw, const float* __restrict__ gnb,
    float* __restrict__ outc, float* __restrict__ outn, float* __restrict__ outh,
    float* __restrict__ outm, u16* __restrict__ gnbf) {
  int b = blockIdx.x >> 3, h = blockIdx.x & 7, t = threadIdx.x;
  int j = (h << 8) + t;
  size_t rg = (size_t)b * 8192;
  float it = G[rg + j], ft = G[rg + 2048 + j], zt = G[rg + 4096 + j], ot = G[rg + 6144 + j];
  size_t idx = (size_t)b * 2048 + j;
  float cp = c1[idx], np = n1[idx], mp = m1[idx];
  float mt = fmaxf(ft + mp, it);
  float ig = expf(it - mt), fg = expf(ft - mt + mp);
  float zg = tanhf(zt), og = 1.f / (1.f + expf(-ot));
  float ct = fg * cp + ig * zg;
  float nt = fg * np + ig;
  float ht = og * (ct / nt);
  outc[idx] = ct; outn[idx] = nt; outh[idx] = ht; outm[idx] = mt;
  float s = ht, q = ht * ht;
  block_reduce2(s, q);
  float mu = s * (1.f / 256.f);
  float var = q * (1.f / 256.f) - mu * mu;
  float xn = (ht - mu) * rsqrtf(var + 1e-5f);
  gnbf[idx] = f2bf(xn * gnw[j] + gnb[j]);
}

// ---------------- out1 + gelu(out2), zero-pad K to 2752 ----------------
__global__ __launch_bounds__(256) void act_gelu(const float* __restrict__ tmp, u16* __restrict__ gl) {
  int i = blockIdx.x * 256 + threadIdx.x;
  int stride = gridDim.x * 256;
  const int total = 8192 * 2752;
  for (; i < total; i += stride) {
    int b = i / 2752, p = i - b * 2752;
    float y = 0.f;
    if (p < 2730) {
      float x1 = tmp[(size_t)b * 5504 + p];
      float x2 = tmp[(size_t)b * 5504 + 2730 + p];
      y = x1 + x2 * 0.5f * (1.f + erff(x2 * 0.70710678118f));
    }
    gl[(size_t)b * 2752 + p] = f2bf(y);
  }
}

extern "C" void kernel_launch(void* const* d_in, const int* in_sizes, int n_in,
                              void* d_out, int out_size, void* d_ws, size_t ws_size,
                              hipStream_t stream) {
  (void)in_sizes; (void)n_in; (void)out_size; (void)ws_size;
  const float* seq = (const float*)d_in[0];
  const float* c1  = (const float*)d_in[1];
  const float* n1  = (const float*)d_in[2];
  const float* h1  = (const float*)d_in[3];
  const float* m1  = (const float*)d_in[4];
  const float* lnw = (const float*)d_in[5];
  const float* lnb = (const float*)d_in[6];
  const float* gnw = (const float*)d_in[7];
  const float* gnb = (const float*)d_in[8];
  const float* Wi = (const float*)d_in[9];  const float* bi  = (const float*)d_in[10];
  const float* Wf = (const float*)d_in[11]; const float* bf_ = (const float*)d_in[12];
  const float* Wz = (const float*)d_in[13]; const float* bz  = (const float*)d_in[14];
  const float* Wo = (const float*)d_in[15]; const float* bo  = (const float*)d_in[16];
  const float* Ri = (const float*)d_in[17]; const float* Rf = (const float*)d_in[18];
  const float* Rz = (const float*)d_in[19]; const float* Ro = (const float*)d_in[20];
  const float* Wup = (const float*)d_in[21]; const float* bup = (const float*)d_in[22];
  const float* Wdn = (const float*)d_in[23]; const float* bdn = (const float*)d_in[24];

  // ---- workspace layout (peak ~474 MB, with reuse) ----
  size_t off = 0;
  char* base = (char*)d_ws;
  auto alloc = [&](size_t bytes) { char* p = base + off; off += (bytes + 255) & ~(size_t)255; return p; };
  u16*   XBF    = (u16*)  alloc((size_t)B_ROWS * 2048 * 2);
  u16*   HBF    = (u16*)  alloc((size_t)B_ROWS * 2048 * 2);
  u16*   WGT    = (u16*)  alloc((size_t)4 * 2048 * 2048 * 2);   // gate weights, B^T
  u16*   RT     = (u16*)  alloc((size_t)4 * 8 * 256 * 256 * 2); // recurrent, B^T per head
  u16*   WUPT   = (u16*)  alloc((size_t)5504 * 2048 * 2);
  u16*   WDNT   = (u16*)  alloc((size_t)2048 * 2752 * 2);
  float* BIASG  = (float*)alloc((size_t)8192 * 4);
  float* BIASUP = (float*)alloc((size_t)5504 * 4);
  u16*   GNBF   = (u16*)  alloc((size_t)B_ROWS * 2048 * 2);
  float* G      = (float*)alloc((size_t)B_ROWS * 8192 * 4);
  float* TMP    = G;            // reuse: G dead after pointwise_gn (180 MB <= 268 MB)
  u16*   GL     = WGT;          // reuse: WGT dead after gates GEMM (45 MB <= 67 MB)

  float* OUT  = (float*)d_out;
  float* OUTC = OUT + (size_t)B_ROWS * 2048;
  float* OUTN = OUTC + (size_t)B_ROWS * 2048;
  float* OUTH = OUTN + (size_t)B_ROWS * 2048;
  float* OUTM = OUTH + (size_t)B_ROWS * 2048;

  dim3 tb32(32, 8);

  // 1) LayerNorm -> bf16
  ln_kernel<<<B_ROWS, 256, 0, stream>>>(seq, lnw, lnb, XBF);
  // 2) h_tm1 -> bf16
  cvt_bf16<<<2048, 256, 0, stream>>>(h1, HBF, B_ROWS * 2048);
  // 3) weight transposes -> bf16 B^T layouts
  transpose_cvt<<<dim3(64, 64, 1), tb32, 0, stream>>>(Wi, 0, 2048, 2048, WGT + (size_t)0 * 4194304, 0, 2048);
  transpose_cvt<<<dim3(64, 64, 1), tb32, 0, stream>>>(Wf, 0, 2048, 2048, WGT + (size_t)1 * 4194304, 0, 2048);
  transpose_cvt<<<dim3(64, 64, 1), tb32, 0, stream>>>(Wz, 0, 2048, 2048, WGT + (size_t)2 * 4194304, 0, 2048);
  transpose_cvt<<<dim3(64, 64, 1), tb32, 0, stream>>>(Wo, 0, 2048, 2048, WGT + (size_t)3 * 4194304, 0, 2048);
  transpose_cvt<<<dim3(8, 8, 8), tb32, 0, stream>>>(Ri, 65536, 256, 256, RT + (size_t)0 * 524288, 65536, 256);
  transpose_cvt<<<dim3(8, 8, 8), tb32, 0, stream>>>(Rf, 65536, 256, 256, RT + (size_t)1 * 524288, 65536, 256);
  transpose_cvt<<<dim3(8, 8, 8), tb32, 0, stream>>>(Rz, 65536, 256, 256, RT + (size_t)2 * 524288, 65536, 256);
  transpose_cvt<<<dim3(8, 8, 8), tb32, 0, stream>>>(Ro, 65536, 256, 256, RT + (size_t)3 * 524288, 65536, 256);
  transpose_cvt<<<dim3(171, 64, 1), tb32, 0, stream>>>(Wup, 0, 2048, 5460, WUPT, 0, 2048);
  transpose_cvt<<<dim3(64, 86, 1), tb32, 0, stream>>>(Wdn, 0, 2730, 2048, WDNT, 0, 2752);
  // 4) biases
  pack_bias<<<32, 256, 0, stream>>>(bi, bf_, bz, bo, bup, BIASG, BIASUP);
  // 5) gates GEMM: G[b, g*2048+n] = x@W_g + b_g + h@R_g (block-diag)
  gemm_bt<<<64 * 64, 256, 0, stream>>>(XBF, 2048, WGT, 2048, 2048,
                                       G, 8192, 8192, 64, BIASG, nullptr, 0, HBF, RT, 1);
  // 6) sLSTM pointwise + GroupNorm; writes c,n,h,m states + bf16 activation
  pointwise_gn<<<B_ROWS * 8, 256, 0, stream>>>(G, c1, n1, m1, gnw, gnb,
                                               OUTC, OUTN, OUTH, OUTM, GNBF);
  // 7) up GEMM (N padded 5460->5504)
  gemm_bt<<<64 * 43, 256, 0, stream>>>(GNBF, 2048, WUPT, 2048, 2048,
                                       TMP, 5504, 5460, 43, BIASUP, nullptr, 0, nullptr, nullptr, 0);
  // 8) out1 + gelu(out2) -> bf16 (K padded 2730->2752 with zeros)
  act_gelu<<<8192, 256, 0, stream>>>(TMP, GL);
  // 9) down GEMM + b_dn + seq residual -> out
  gemm_bt<<<64 * 16, 256, 0, stream>>>(GL, 2752, WDNT, 2752, 2752,
                                       OUT, 2048, 2048, 16, bdn, seq, 2048, nullptr, nullptr, 0);
}

// Round 4
// 1649.053 us; speedup vs baseline: 1.1304x; 1.1304x over previous
//
#include <hip/hip_runtime.h>
#include <math.h>

typedef unsigned short u16;
typedef __attribute__((ext_vector_type(4))) float f32x4;
typedef __attribute__((ext_vector_type(8))) short bf16x8;
typedef __attribute__((ext_vector_type(8))) unsigned short u16x8;

#define B_ROWS 8192
#define GLDS(gaddr, laddr)                                                                  \
  __builtin_amdgcn_global_load_lds(                                                        \
      (const __attribute__((address_space(1))) unsigned int*)(const void*)(gaddr),          \
      (__attribute__((address_space(3))) unsigned int*)(void*)(laddr), 16, 0, 0)

__device__ __forceinline__ u16 f2bf(float f) {
  unsigned int u = __float_as_uint(f);
  unsigned int r = u + 0x7fffu + ((u >> 16) & 1u);
  return (u16)(r >> 16);
}

// ---------------- block-wide (256 thr) dual reduction ----------------
__device__ __forceinline__ void block_reduce2(float& a, float& b) {
  __shared__ float sb[8];
  #pragma unroll
  for (int off = 32; off > 0; off >>= 1) {
    a += __shfl_down(a, off, 64);
    b += __shfl_down(b, off, 64);
  }
  int lane = threadIdx.x & 63, wid = threadIdx.x >> 6;
  if (lane == 0) { sb[wid] = a; sb[wid + 4] = b; }
  __syncthreads();
  a = sb[0] + sb[1] + sb[2] + sb[3];
  b = sb[4] + sb[5] + sb[6] + sb[7];
  __syncthreads();
}

// ---------------- LayerNorm (2048 cols) -> bf16 ----------------
__global__ __launch_bounds__(256) void ln_kernel(const float* __restrict__ seq,
                                                 const float* __restrict__ w,
                                                 const float* __restrict__ b,
                                                 u16* __restrict__ xbf) {
  int row = blockIdx.x, t = threadIdx.x;
  const f32x4* x = (const f32x4*)(seq + (size_t)row * 2048);
  f32x4 v0 = x[2 * t], v1 = x[2 * t + 1];
  float s = 0.f, q = 0.f;
  #pragma unroll
  for (int i = 0; i < 4; ++i) { s += v0[i] + v1[i]; q += v0[i] * v0[i] + v1[i] * v1[i]; }
  block_reduce2(s, q);
  float mu = s * (1.f / 2048.f);
  float var = q * (1.f / 2048.f) - mu * mu;
  float rstd = rsqrtf(var + 1e-5f);
  f32x4 w0 = ((const f32x4*)w)[2 * t], w1 = ((const f32x4*)w)[2 * t + 1];
  f32x4 b0 = ((const f32x4*)b)[2 * t], b1 = ((const f32x4*)b)[2 * t + 1];
  u16x8 o;
  #pragma unroll
  for (int i = 0; i < 4; ++i) o[i] = f2bf((v0[i] - mu) * rstd * w0[i] + b0[i]);
  #pragma unroll
  for (int i = 0; i < 4; ++i) o[4 + i] = f2bf((v1[i] - mu) * rstd * w1[i] + b1[i]);
  ((u16x8*)(xbf + (size_t)row * 2048))[t] = o;
}

// ---------------- fp32 -> bf16 elementwise ----------------
__global__ __launch_bounds__(256) void cvt_bf16(const float* __restrict__ in,
                                                u16* __restrict__ out, int n) {
  int i = blockIdx.x * 256 + threadIdx.x;
  int stride = gridDim.x * 256;
  for (; i < n; i += stride) out[i] = f2bf(in[i]);
}

// ---------------- transpose + cvt: out[c][r] = bf16(in[r][c]) ----------------
__global__ void transpose_cvt(const float* __restrict__ in, long ibstride, int R, int Cc,
                              u16* __restrict__ out, long obstride, int ldo) {
  in += (size_t)blockIdx.z * ibstride;
  out += (size_t)blockIdx.z * obstride;
  __shared__ float tile[32][33];
  int c0 = blockIdx.x * 32, r0 = blockIdx.y * 32;
  int tx = threadIdx.x, ty = threadIdx.y;
  #pragma unroll
  for (int j = 0; j < 4; ++j) {
    int rr = r0 + ty + j * 8;
    if (rr < R && c0 + tx < Cc) tile[ty + j * 8][tx] = in[(size_t)rr * Cc + c0 + tx];
  }
  __syncthreads();
  #pragma unroll
  for (int j = 0; j < 4; ++j) {
    int cc = c0 + ty + j * 8, rr = r0 + tx;
    if (cc < Cc && rr < R) out[(size_t)cc * ldo + rr] = f2bf(tile[tx][ty + j * 8]);
  }
}

// ---------------- bias packing ----------------
__global__ __launch_bounds__(256) void pack_bias(const float* __restrict__ bi, const float* __restrict__ bf_,
                                                 const float* __restrict__ bz, const float* __restrict__ bo,
                                                 const float* __restrict__ bup,
                                                 float* __restrict__ biasg, float* __restrict__ biasup) {
  int i = blockIdx.x * 256 + threadIdx.x;
  if (i < 8192) {
    int g = i >> 11, j = i & 2047;
    const float* p = (g == 0) ? bi : (g == 1) ? bf_ : (g == 2) ? bz : bo;
    biasg[i] = p[j];
  }
  if (i < 5504) biasup[i] = (i < 5460) ? bup[i] : 0.f;
}

// =====================================================================
// 256x256 tile, BK=64, 8-wave (2Mx4N), 8-phase counted-vmcnt MFMA GEMM.
// A[M][K] x Bt[N][K] -> C fp32 (+bias, +addsrc). REC=1 appends 4 K-tiles
// of the block-diagonal recurrent product h[:,head*256:+256] @ R[head].
// LDS: [dbuf][khalf][256][32] per operand; K-half tiles are contiguous
// global_load_lds targets. Bank swizzle s' = s ^ ((row>>1)&3) applied by
// pre-swizzling the per-lane GLOBAL source address (LDS write stays linear).
// Staging stream (phases of tile t): P1:Akh1(t+1) P2:Bkh1(t+1)
// P3:Akh0(t+2) P4:Bkh0(t+2); vmcnt(4) at end of each tile guarantees all
// of tile t+1 landed while 2 half-tiles of t+2 stay in flight.
// =====================================================================
template<int REC>
__global__ __launch_bounds__(512, 2) void gemm256(
    const u16* __restrict__ A, int lda,
    const u16* __restrict__ Bt, int ldb, int KT,
    float* __restrict__ C, long ldc, int Nvalid, int ntN,
    const float* __restrict__ bias,
    const float* __restrict__ addsrc, int ldadd,
    const u16* __restrict__ hbf, const u16* __restrict__ RTw) {
  __shared__ __align__(16) u16 Al[2][2][256][32];
  __shared__ __align__(16) u16 Bl[2][2][256][32];
  const int NT = KT + (REC ? 4 : 0);

  int nb = gridDim.x;
  int bid = blockIdx.x;
  int per = nb >> 3;                       // grids are multiples of 8
  int id = (bid & 7) * per + (bid >> 3);   // XCD-aware swizzle (bijective)
  int m0 = (id / ntN) * 256, n0 = (id % ntN) * 256;

  int tid = threadIdx.x, lane = tid & 63, wave = tid >> 6;
  int wm = wave >> 2, wn = wave & 3;       // 2 x 4 wave grid
  int r = lane & 15, sgrp = lane >> 4;

  const u16* rsrc = nullptr; int hcol = 0;
  if (REC) {
    int g = n0 >> 11, head = (n0 & 2047) >> 8;
    rsrc = RTw + ((size_t)(g * 8 + head)) * 65536;
    hcol = head * 256;
  }

  auto stage = [&](int tt, int which) {    // which: 0=Akh0 1=Akh1 2=Bkh0 3=Bkh1
    if (tt >= NT) return;
    const int isA = (which < 2), kh = which & 1, slot = tt & 1;
    const u16* src; size_t ld;
    if (!REC || tt < KT) {
      if (isA) { src = A + (size_t)m0 * lda + tt * 64; ld = lda; }
      else     { src = Bt + (size_t)n0 * ldb + tt * 64; ld = ldb; }
    } else {
      int t2 = tt - KT;
      if (isA) { src = hbf + (size_t)m0 * 2048 + hcol + t2 * 64; ld = 2048; }
      else     { src = rsrc + t2 * 64; ld = 256; }
    }
    u16* base = isA ? &Al[slot][kh][0][0] : &Bl[slot][kh][0][0];
    #pragma unroll
    for (int c = 0; c < 2; ++c) {
      int R0 = wave * 32 + c * 16;                 // wave-uniform
      int row = R0 + (lane >> 2);
      int s = (lane & 3) ^ ((row >> 1) & 3);       // inverse-swizzled source
      GLDS(src + (size_t)row * ld + kh * 32 + s * 8, base + R0 * 32);
    }
  };

  auto ldfragA = [&](int slot, int ks, int row) -> bf16x8 {
    int s = sgrp ^ ((row >> 1) & 3);
    return *(const bf16x8*)(&Al[slot][ks][0][0] + row * 32 + s * 8);
  };
  auto ldfragB = [&](int slot, int ks, int row) -> bf16x8 {
    int s = sgrp ^ ((row >> 1) & 3);
    return *(const bf16x8*)(&Bl[slot][ks][0][0] + row * 32 + s * 8);
  };

  f32x4 acc[8][4] = {};
  bf16x8 af[4], bfr[4];

  // ---- prologue: tile0 (4 halves) + tile1 {Akh0,Bkh0} ----
  stage(0, 0); stage(0, 2); stage(0, 1); stage(0, 3);
  stage(1, 0); stage(1, 2);
  asm volatile("s_waitcnt vmcnt(4)" ::: "memory");
  __builtin_amdgcn_s_barrier();

  for (int t = 0; t < NT; ++t) {
    int slot = t & 1;
    // ---- P1: ks=0, mh=0, load B ----
    #pragma unroll
    for (int mi = 0; mi < 4; ++mi) af[mi] = ldfragA(slot, 0, wm * 128 + mi * 16 + r);
    #pragma unroll
    for (int ni = 0; ni < 4; ++ni) bfr[ni] = ldfragB(slot, 0, wn * 64 + ni * 16 + r);
    stage(t + 1, 1);
    __builtin_amdgcn_s_barrier();
    asm volatile("s_waitcnt lgkmcnt(0)" ::: "memory");
    __builtin_amdgcn_s_setprio(1);
    #pragma unroll
    for (int mi = 0; mi < 4; ++mi)
      #pragma unroll
      for (int ni = 0; ni < 4; ++ni)
        acc[mi][ni] = __builtin_amdgcn_mfma_f32_16x16x32_bf16(af[mi], bfr[ni], acc[mi][ni], 0, 0, 0);
    __builtin_amdgcn_s_setprio(0);
    __builtin_amdgcn_s_barrier();
    // ---- P2: ks=0, mh=1, reuse B ----
    #pragma unroll
    for (int mi = 0; mi < 4; ++mi) af[mi] = ldfragA(slot, 0, wm * 128 + 64 + mi * 16 + r);
    stage(t + 1, 3);
    __builtin_amdgcn_s_barrier();
    asm volatile("s_waitcnt lgkmcnt(0)" ::: "memory");
    __builtin_amdgcn_s_setprio(1);
    #pragma unroll
    for (int mi = 0; mi < 4; ++mi)
      #pragma unroll
      for (int ni = 0; ni < 4; ++ni)
        acc[4 + mi][ni] = __builtin_amdgcn_mfma_f32_16x16x32_bf16(af[mi], bfr[ni], acc[4 + mi][ni], 0, 0, 0);
    __builtin_amdgcn_s_setprio(0);
    __builtin_amdgcn_s_barrier();
    // ---- P3: ks=1, mh=0, load B ----
    #pragma unroll
    for (int mi = 0; mi < 4; ++mi) af[mi] = ldfragA(slot, 1, wm * 128 + mi * 16 + r);
    #pragma unroll
    for (int ni = 0; ni < 4; ++ni) bfr[ni] = ldfragB(slot, 1, wn * 64 + ni * 16 + r);
    stage(t + 2, 0);
    __builtin_amdgcn_s_barrier();
    asm volatile("s_waitcnt lgkmcnt(0)" ::: "memory");
    __builtin_amdgcn_s_setprio(1);
    #pragma unroll
    for (int mi = 0; mi < 4; ++mi)
      #pragma unroll
      for (int ni = 0; ni < 4; ++ni)
        acc[mi][ni] = __builtin_amdgcn_mfma_f32_16x16x32_bf16(af[mi], bfr[ni], acc[mi][ni], 0, 0, 0);
    __builtin_amdgcn_s_setprio(0);
    __builtin_amdgcn_s_barrier();
    // ---- P4: ks=1, mh=1, reuse B; counted vmcnt at tile end ----
    #pragma unroll
    for (int mi = 0; mi < 4; ++mi) af[mi] = ldfragA(slot, 1, wm * 128 + 64 + mi * 16 + r);
    stage(t + 2, 2);
    __builtin_amdgcn_s_barrier();
    asm volatile("s_waitcnt lgkmcnt(0)" ::: "memory");
    __builtin_amdgcn_s_setprio(1);
    #pragma unroll
    for (int mi = 0; mi < 4; ++mi)
      #pragma unroll
      for (int ni = 0; ni < 4; ++ni)
        acc[4 + mi][ni] = __builtin_amdgcn_mfma_f32_16x16x32_bf16(af[mi], bfr[ni], acc[4 + mi][ni], 0, 0, 0);
    __builtin_amdgcn_s_setprio(0);
    if (t + 2 < NT)      { asm volatile("s_waitcnt vmcnt(4)" ::: "memory"); }
    else if (t + 1 < NT) { asm volatile("s_waitcnt vmcnt(0)" ::: "memory"); }
    __builtin_amdgcn_s_barrier();
  }

  // ---- epilogue ----
  #pragma unroll
  for (int a = 0; a < 8; ++a) {
    int row0 = m0 + wm * 128 + a * 16 + sgrp * 4;
    #pragma unroll
    for (int ni = 0; ni < 4; ++ni) {
      int col = n0 + wn * 64 + ni * 16 + r;
      if (col >= Nvalid) continue;
      float bv = bias ? bias[col] : 0.f;
      #pragma unroll
      for (int jj = 0; jj < 4; ++jj) {
        float v = acc[a][ni][jj] + bv;
        if (addsrc) v += addsrc[(size_t)(row0 + jj) * ldadd + col];
        C[(size_t)(row0 + jj) * ldc + col] = v;
      }
    }
  }
}

// ---------------- sLSTM pointwise + GroupNorm (block = one (row, head)) ----------------
__global__ __launch_bounds__(256) void pointwise_gn(
    const float* __restrict__ G, const float* __restrict__ c1, const float* __restrict__ n1,
    const float* __restrict__ m1, const float* __restrict__ gnw, const float* __restrict__ gnb,
    float* __restrict__ outc, float* __restrict__ outn, float* __restrict__ outh,
    float* __restrict__ outm, u16* __restrict__ gnbf) {
  int b = blockIdx.x >> 3, h = blockIdx.x & 7, t = threadIdx.x;
  int j = (h << 8) + t;
  size_t rg = (size_t)b * 8192;
  float it = G[rg + j], ft = G[rg + 2048 + j], zt = G[rg + 4096 + j], ot = G[rg + 6144 + j];
  size_t idx = (size_t)b * 2048 + j;
  float cp = c1[idx], np = n1[idx], mp = m1[idx];
  float mt = fmaxf(ft + mp, it);
  float ig = expf(it - mt), fg = expf(ft - mt + mp);
  float zg = tanhf(zt), og = 1.f / (1.f + expf(-ot));
  float ct = fg * cp + ig * zg;
  float nt = fg * np + ig;
  float ht = og * (ct / nt);
  outc[idx] = ct; outn[idx] = nt; outh[idx] = ht; outm[idx] = mt;
  float s = ht, q = ht * ht;
  block_reduce2(s, q);
  float mu = s * (1.f / 256.f);
  float var = q * (1.f / 256.f) - mu * mu;
  float xn = (ht - mu) * rsqrtf(var + 1e-5f);
  gnbf[idx] = f2bf(xn * gnw[j] + gnb[j]);
}

// ---------------- out1 + gelu(out2), zero-pad K to 2752 ----------------
__global__ __launch_bounds__(256) void act_gelu(const float* __restrict__ tmp, u16* __restrict__ gl) {
  int i = blockIdx.x * 256 + threadIdx.x;
  int stride = gridDim.x * 256;
  const int total = 8192 * 2752;
  for (; i < total; i += stride) {
    int b = i / 2752, p = i - b * 2752;
    float y = 0.f;
    if (p < 2730) {
      float x1 = tmp[(size_t)b * 5504 + p];
      float x2 = tmp[(size_t)b * 5504 + 2730 + p];
      y = x1 + x2 * 0.5f * (1.f + erff(x2 * 0.70710678118f));
    }
    gl[(size_t)b * 2752 + p] = f2bf(y);
  }
}

extern "C" void kernel_launch(void* const* d_in, const int* in_sizes, int n_in,
                              void* d_out, int out_size, void* d_ws, size_t ws_size,
                              hipStream_t stream) {
  (void)in_sizes; (void)n_in; (void)out_size; (void)ws_size;
  const float* seq = (const float*)d_in[0];
  const float* c1  = (const float*)d_in[1];
  const float* n1  = (const float*)d_in[2];
  const float* h1  = (const float*)d_in[3];
  const float* m1  = (const float*)d_in[4];
  const float* lnw = (const float*)d_in[5];
  const float* lnb = (const float*)d_in[6];
  const float* gnw = (const float*)d_in[7];
  const float* gnb = (const float*)d_in[8];
  const float* Wi = (const float*)d_in[9];  const float* bi  = (const float*)d_in[10];
  const float* Wf = (const float*)d_in[11]; const float* bf_ = (const float*)d_in[12];
  const float* Wz = (const float*)d_in[13]; const float* bz  = (const float*)d_in[14];
  const float* Wo = (const float*)d_in[15]; const float* bo  = (const float*)d_in[16];
  const float* Ri = (const float*)d_in[17]; const float* Rf = (const float*)d_in[18];
  const float* Rz = (const float*)d_in[19]; const float* Ro = (const float*)d_in[20];
  const float* Wup = (const float*)d_in[21]; const float* bup = (const float*)d_in[22];
  const float* Wdn = (const float*)d_in[23]; const float* bdn = (const float*)d_in[24];

  // ---- workspace layout (peak ~475 MB, with reuse) ----
  size_t off = 0;
  char* base = (char*)d_ws;
  auto alloc = [&](size_t bytes) { char* p = base + off; off += (bytes + 255) & ~(size_t)255; return p; };
  u16*   XBF    = (u16*)  alloc((size_t)B_ROWS * 2048 * 2);
  u16*   HBF    = (u16*)  alloc((size_t)B_ROWS * 2048 * 2);
  u16*   WGT    = (u16*)  alloc((size_t)4 * 2048 * 2048 * 2);   // gate weights, B^T
  u16*   RT     = (u16*)  alloc((size_t)4 * 8 * 256 * 256 * 2); // recurrent, B^T per head
  u16*   WUPT   = (u16*)  alloc((size_t)5632 * 2048 * 2);       // N padded to 22*256
  u16*   WDNT   = (u16*)  alloc((size_t)2048 * 2752 * 2);
  float* BIASG  = (float*)alloc((size_t)8192 * 4);
  float* BIASUP = (float*)alloc((size_t)5504 * 4);
  u16*   GNBF   = (u16*)  alloc((size_t)B_ROWS * 2048 * 2);
  float* G      = (float*)alloc((size_t)B_ROWS * 8192 * 4);
  float* TMP    = G;            // reuse: G dead after pointwise_gn (180 MB <= 268 MB)
  u16*   GL     = WGT;          // reuse: WGT dead after gates GEMM (45 MB <= 67 MB)

  float* OUT  = (float*)d_out;
  float* OUTC = OUT + (size_t)B_ROWS * 2048;
  float* OUTN = OUTC + (size_t)B_ROWS * 2048;
  float* OUTH = OUTN + (size_t)B_ROWS * 2048;
  float* OUTM = OUTH + (size_t)B_ROWS * 2048;

  dim3 tb32(32, 8);

  // 1) LayerNorm -> bf16
  ln_kernel<<<B_ROWS, 256, 0, stream>>>(seq, lnw, lnb, XBF);
  // 2) h_tm1 -> bf16
  cvt_bf16<<<2048, 256, 0, stream>>>(h1, HBF, B_ROWS * 2048);
  // 3) weight transposes -> bf16 B^T layouts
  transpose_cvt<<<dim3(64, 64, 1), tb32, 0, stream>>>(Wi, 0, 2048, 2048, WGT + (size_t)0 * 4194304, 0, 2048);
  transpose_cvt<<<dim3(64, 64, 1), tb32, 0, stream>>>(Wf, 0, 2048, 2048, WGT + (size_t)1 * 4194304, 0, 2048);
  transpose_cvt<<<dim3(64, 64, 1), tb32, 0, stream>>>(Wz, 0, 2048, 2048, WGT + (size_t)2 * 4194304, 0, 2048);
  transpose_cvt<<<dim3(64, 64, 1), tb32, 0, stream>>>(Wo, 0, 2048, 2048, WGT + (size_t)3 * 4194304, 0, 2048);
  transpose_cvt<<<dim3(8, 8, 8), tb32, 0, stream>>>(Ri, 65536, 256, 256, RT + (size_t)0 * 524288, 65536, 256);
  transpose_cvt<<<dim3(8, 8, 8), tb32, 0, stream>>>(Rf, 65536, 256, 256, RT + (size_t)1 * 524288, 65536, 256);
  transpose_cvt<<<dim3(8, 8, 8), tb32, 0, stream>>>(Rz, 65536, 256, 256, RT + (size_t)2 * 524288, 65536, 256);
  transpose_cvt<<<dim3(8, 8, 8), tb32, 0, stream>>>(Ro, 65536, 256, 256, RT + (size_t)3 * 524288, 65536, 256);
  transpose_cvt<<<dim3(171, 64, 1), tb32, 0, stream>>>(Wup, 0, 2048, 5460, WUPT, 0, 2048);
  transpose_cvt<<<dim3(64, 86, 1), tb32, 0, stream>>>(Wdn, 0, 2730, 2048, WDNT, 0, 2752);
  // 4) biases
  pack_bias<<<32, 256, 0, stream>>>(bi, bf_, bz, bo, bup, BIASG, BIASUP);
  // 5) gates GEMM: G[b, g*2048+n] = x@W_g + b_g + h@R_g (block-diag fused as 4 extra K-tiles)
  gemm256<1><<<32 * 32, 512, 0, stream>>>(XBF, 2048, WGT, 2048, 32,
                                          G, 8192, 8192, 32, BIASG, nullptr, 0, HBF, RT);
  // 6) sLSTM pointwise + GroupNorm; writes c,n,h,m states + bf16 activation
  pointwise_gn<<<B_ROWS * 8, 256, 0, stream>>>(G, c1, n1, m1, gnw, gnb,
                                               OUTC, OUTN, OUTH, OUTM, GNBF);
  // 7) up GEMM (N tiles 22 -> 5632, stores guarded at 5460; TMP row stride stays 5504)
  gemm256<0><<<32 * 22, 512, 0, stream>>>(GNBF, 2048, WUPT, 2048, 32,
                                          TMP, 5504, 5460, 22, BIASUP, nullptr, 0, nullptr, nullptr);
  // 8) out1 + gelu(out2) -> bf16 (K padded 2730->2752 with zeros)
  act_gelu<<<8192, 256, 0, stream>>>(TMP, GL);
  // 9) down GEMM + b_dn + seq residual -> out
  gemm256<0><<<32 * 8, 512, 0, stream>>>(GL, 2752, WDNT, 2752, 43,
                                         OUT, 2048, 2048, 8, bdn, seq, 2048, nullptr, nullptr);
}

// Round 5
// 1510.806 us; speedup vs baseline: 1.2338x; 1.0915x over previous
//
#include <hip/hip_runtime.h>
#include <math.h>

typedef unsigned short u16;
typedef __attribute__((ext_vector_type(4))) float f32x4;
typedef __attribute__((ext_vector_type(8))) short bf16x8;
typedef __attribute__((ext_vector_type(8))) unsigned short u16x8;

#define B_ROWS 8192
#define GLDS(gaddr, laddr)                                                                  \
  __builtin_amdgcn_global_load_lds(                                                        \
      (const __attribute__((address_space(1))) unsigned int*)(const void*)(gaddr),          \
      (__attribute__((address_space(3))) unsigned int*)(void*)(laddr), 16, 0, 0)

__device__ __forceinline__ u16 f2bf(float f) {
  unsigned int u = __float_as_uint(f);
  unsigned int r = u + 0x7fffu + ((u >> 16) & 1u);
  return (u16)(r >> 16);
}

// inline-asm LDS read: invisible to LLVM's LDS-DMA alias tracking, so the
// compiler cannot insert its own vmcnt drains before it (rule 18 pattern).
__device__ __forceinline__ bf16x8 dsr(unsigned a) {
  bf16x8 d;
  asm volatile("ds_read_b128 %0, %1" : "=v"(d) : "v"(a));
  return d;
}

// ---------------- block-wide (256 thr) dual reduction ----------------
__device__ __forceinline__ void block_reduce2(float& a, float& b) {
  __shared__ float sb[8];
  #pragma unroll
  for (int off = 32; off > 0; off >>= 1) {
    a += __shfl_down(a, off, 64);
    b += __shfl_down(b, off, 64);
  }
  int lane = threadIdx.x & 63, wid = threadIdx.x >> 6;
  if (lane == 0) { sb[wid] = a; sb[wid + 4] = b; }
  __syncthreads();
  a = sb[0] + sb[1] + sb[2] + sb[3];
  b = sb[4] + sb[5] + sb[6] + sb[7];
  __syncthreads();
}

// ---------------- LayerNorm (2048 cols) -> bf16 ----------------
__global__ __launch_bounds__(256) void ln_kernel(const float* __restrict__ seq,
                                                 const float* __restrict__ w,
                                                 const float* __restrict__ b,
                                                 u16* __restrict__ xbf) {
  int row = blockIdx.x, t = threadIdx.x;
  const f32x4* x = (const f32x4*)(seq + (size_t)row * 2048);
  f32x4 v0 = x[2 * t], v1 = x[2 * t + 1];
  float s = 0.f, q = 0.f;
  #pragma unroll
  for (int i = 0; i < 4; ++i) { s += v0[i] + v1[i]; q += v0[i] * v0[i] + v1[i] * v1[i]; }
  block_reduce2(s, q);
  float mu = s * (1.f / 2048.f);
  float var = q * (1.f / 2048.f) - mu * mu;
  float rstd = rsqrtf(var + 1e-5f);
  f32x4 w0 = ((const f32x4*)w)[2 * t], w1 = ((const f32x4*)w)[2 * t + 1];
  f32x4 b0 = ((const f32x4*)b)[2 * t], b1 = ((const f32x4*)b)[2 * t + 1];
  u16x8 o;
  #pragma unroll
  for (int i = 0; i < 4; ++i) o[i] = f2bf((v0[i] - mu) * rstd * w0[i] + b0[i]);
  #pragma unroll
  for (int i = 0; i < 4; ++i) o[4 + i] = f2bf((v1[i] - mu) * rstd * w1[i] + b1[i]);
  ((u16x8*)(xbf + (size_t)row * 2048))[t] = o;
}

// ---------------- fp32 -> bf16 elementwise ----------------
__global__ __launch_bounds__(256) void cvt_bf16(const float* __restrict__ in,
                                                u16* __restrict__ out, int n) {
  int i = blockIdx.x * 256 + threadIdx.x;
  int stride = gridDim.x * 256;
  for (; i < n; i += stride) out[i] = f2bf(in[i]);
}

// ---------------- transpose + cvt: out[c][r] = bf16(in[r][c]) ----------------
__global__ void transpose_cvt(const float* __restrict__ in, long ibstride, int R, int Cc,
                              u16* __restrict__ out, long obstride, int ldo) {
  in += (size_t)blockIdx.z * ibstride;
  out += (size_t)blockIdx.z * obstride;
  __shared__ float tile[32][33];
  int c0 = blockIdx.x * 32, r0 = blockIdx.y * 32;
  int tx = threadIdx.x, ty = threadIdx.y;
  #pragma unroll
  for (int j = 0; j < 4; ++j) {
    int rr = r0 + ty + j * 8;
    if (rr < R && c0 + tx < Cc) tile[ty + j * 8][tx] = in[(size_t)rr * Cc + c0 + tx];
  }
  __syncthreads();
  #pragma unroll
  for (int j = 0; j < 4; ++j) {
    int cc = c0 + ty + j * 8, rr = r0 + tx;
    if (cc < Cc && rr < R) out[(size_t)cc * ldo + rr] = f2bf(tile[tx][ty + j * 8]);
  }
}

// ---------------- bias packing ----------------
__global__ __launch_bounds__(256) void pack_bias(const float* __restrict__ bi, const float* __restrict__ bf_,
                                                 const float* __restrict__ bz, const float* __restrict__ bo,
                                                 const float* __restrict__ bup,
                                                 float* __restrict__ biasg, float* __restrict__ biasup) {
  int i = blockIdx.x * 256 + threadIdx.x;
  if (i < 8192) {
    int g = i >> 11, j = i & 2047;
    const float* p = (g == 0) ? bi : (g == 1) ? bf_ : (g == 2) ? bz : bo;
    biasg[i] = p[j];
  }
  if (i < 5504) biasup[i] = (i < 5460) ? bup[i] : 0.f;
}

#define MFMA_CLUSTER(lo)                                                                   \
  __builtin_amdgcn_s_setprio(1);                                                           \
  _Pragma("unroll")                                                                        \
  for (int mi = 0; mi < 4; ++mi)                                                           \
    _Pragma("unroll")                                                                      \
    for (int ni = 0; ni < 4; ++ni)                                                         \
      acc[(lo) + mi][ni] =                                                                 \
          __builtin_amdgcn_mfma_f32_16x16x32_bf16(af[mi], bfr[ni], acc[(lo) + mi][ni], 0, 0, 0); \
  __builtin_amdgcn_s_setprio(0);

#define WAIT_LDS()                                                                         \
  asm volatile("s_waitcnt lgkmcnt(0)" ::: "memory");                                       \
  __builtin_amdgcn_sched_barrier(0);

// =====================================================================
// 256x256 tile, BK=64, 8-wave (2Mx4N), 8-phase counted-vmcnt MFMA GEMM.
// Fragment loads are inline-asm ds_read_b128 so the compiler's LDS-DMA
// alias tracking cannot insert vmcnt drains; the manual ledger below is
// the sole GLDS->read guard (audited):
//   staging per tile t: P1:Akh1(t+1) P2:Bkh1(t+1) P3:Akh0(t+2) P4:Bkh0(t+2)
//   vmcnt(4) at tile end => all of tile t+1 landed, kh0(t+2) in flight.
// Bank swizzle s' = s ^ ((row>>1)&3): applied on the per-lane GLOBAL source
// (LDS dest stays linear) and on the LDS read address (involution, rule 21).
// =====================================================================
template<int REC>
__global__ __launch_bounds__(512, 2) void gemm256(
    const u16* __restrict__ A, int lda,
    const u16* __restrict__ Bt, int ldb, int KT,
    float* __restrict__ C, long ldc, int Nvalid, int ntN,
    const float* __restrict__ bias,
    const float* __restrict__ addsrc, int ldadd,
    const u16* __restrict__ hbf, const u16* __restrict__ RTw) {
  __shared__ __align__(16) u16 Al[2][2][256][32];
  __shared__ __align__(16) u16 Bl[2][2][256][32];
  const int NT = KT + (REC ? 4 : 0);

  int nb = gridDim.x;
  int bid = blockIdx.x;
  int per = nb >> 3;                       // grids are multiples of 8
  int id = (bid & 7) * per + (bid >> 3);   // XCD-aware swizzle (bijective)
  int m0 = (id / ntN) * 256, n0 = (id % ntN) * 256;

  int tid = threadIdx.x, lane = tid & 63, wave = tid >> 6;
  int wm = wave >> 2, wn = wave & 3;       // 2 x 4 wave grid
  int r = lane & 15, sgrp = lane >> 4;

  const u16* rsrc = nullptr; int hcol = 0;
  if (REC) {
    int g = n0 >> 11, head = (n0 & 2047) >> 8;
    rsrc = RTw + ((size_t)(g * 8 + head)) * 65536;
    hcol = head * 256;
  }

  auto stage = [&](int tt, int which) {    // which: 0=Akh0 1=Akh1 2=Bkh0 3=Bkh1
    if (tt >= NT) return;
    const int isA = (which < 2), kh = which & 1, slot = tt & 1;
    const u16* src; size_t ld;
    if (!REC || tt < KT) {
      if (isA) { src = A + (size_t)m0 * lda + tt * 64; ld = lda; }
      else     { src = Bt + (size_t)n0 * ldb + tt * 64; ld = ldb; }
    } else {
      int t2 = tt - KT;
      if (isA) { src = hbf + (size_t)m0 * 2048 + hcol + t2 * 64; ld = 2048; }
      else     { src = rsrc + t2 * 64; ld = 256; }
    }
    u16* base = isA ? &Al[slot][kh][0][0] : &Bl[slot][kh][0][0];
    #pragma unroll
    for (int c = 0; c < 2; ++c) {
      int R0 = wave * 32 + c * 16;                 // wave-uniform
      int row = R0 + (lane >> 2);
      int s = (lane & 3) ^ ((row >> 1) & 3);       // inverse-swizzled source
      GLDS(src + (size_t)row * ld + kh * 32 + s * 8, base + R0 * 32);
    }
  };

  // 32-bit LDS byte addresses for inline-asm reads
  unsigned AlB = (unsigned)(size_t)(__attribute__((address_space(3))) u16*)&Al[0][0][0][0];
  unsigned BlB = (unsigned)(size_t)(__attribute__((address_space(3))) u16*)&Bl[0][0][0][0];
  int sA = sgrp ^ ((r >> 1) & 3);                          // same for all mi/ni (mi*16>>1 ≡ 0 mod 4)
  unsigned aBaseT = AlB + (unsigned)((wm * 128 + r) * 64 + sA * 16);
  unsigned bBaseT = BlB + (unsigned)((wn * 64 + r) * 64 + sA * 16);

  f32x4 acc[8][4] = {};
  bf16x8 af[4], bfr[4];

  // ---- prologue: tile0 (4 halves) + tile1 {Akh0,Bkh0} ----
  stage(0, 0); stage(0, 2); stage(0, 1); stage(0, 3);
  stage(1, 0); stage(1, 2);
  asm volatile("s_waitcnt vmcnt(4)" ::: "memory");
  __builtin_amdgcn_s_barrier();

  for (int t = 0; t < NT; ++t) {
    unsigned sl = (unsigned)(t & 1) * 32768u;
    unsigned ab = aBaseT + sl, bb = bBaseT + sl;
    // ---- P1: ks=0, mh=0, load B ----
    af[0] = dsr(ab);          af[1] = dsr(ab + 1024);
    af[2] = dsr(ab + 2048);   af[3] = dsr(ab + 3072);
    bfr[0] = dsr(bb);         bfr[1] = dsr(bb + 1024);
    bfr[2] = dsr(bb + 2048);  bfr[3] = dsr(bb + 3072);
    stage(t + 1, 1);
    __builtin_amdgcn_s_barrier();
    WAIT_LDS();
    MFMA_CLUSTER(0);
    __builtin_amdgcn_s_barrier();
    // ---- P2: ks=0, mh=1, reuse B ----
    af[0] = dsr(ab + 4096);   af[1] = dsr(ab + 5120);
    af[2] = dsr(ab + 6144);   af[3] = dsr(ab + 7168);
    stage(t + 1, 3);
    __builtin_amdgcn_s_barrier();
    WAIT_LDS();
    MFMA_CLUSTER(4);
    __builtin_amdgcn_s_barrier();
    // ---- P3: ks=1, mh=0, load B ----
    af[0] = dsr(ab + 16384);  af[1] = dsr(ab + 17408);
    af[2] = dsr(ab + 18432);  af[3] = dsr(ab + 19456);
    bfr[0] = dsr(bb + 16384); bfr[1] = dsr(bb + 17408);
    bfr[2] = dsr(bb + 18432); bfr[3] = dsr(bb + 19456);
    stage(t + 2, 0);
    __builtin_amdgcn_s_barrier();
    WAIT_LDS();
    MFMA_CLUSTER(0);
    __builtin_amdgcn_s_barrier();
    // ---- P4: ks=1, mh=1, reuse B; counted vmcnt at tile end ----
    af[0] = dsr(ab + 20480);  af[1] = dsr(ab + 21504);
    af[2] = dsr(ab + 22528);  af[3] = dsr(ab + 23552);
    stage(t + 2, 2);
    __builtin_amdgcn_s_barrier();
    WAIT_LDS();
    MFMA_CLUSTER(4);
    if (t + 2 < NT)      { asm volatile("s_waitcnt vmcnt(4)" ::: "memory"); }
    else if (t + 1 < NT) { asm volatile("s_waitcnt vmcnt(0)" ::: "memory"); }
    __builtin_amdgcn_s_barrier();
  }

  // ---- epilogue ----
  #pragma unroll
  for (int a = 0; a < 8; ++a) {
    int row0 = m0 + wm * 128 + a * 16 + sgrp * 4;
    #pragma unroll
    for (int ni = 0; ni < 4; ++ni) {
      int col = n0 + wn * 64 + ni * 16 + r;
      if (col >= Nvalid) continue;
      float bv = bias ? bias[col] : 0.f;
      #pragma unroll
      for (int jj = 0; jj < 4; ++jj) {
        float v = acc[a][ni][jj] + bv;
        if (addsrc) v += addsrc[(size_t)(row0 + jj) * ldadd + col];
        C[(size_t)(row0 + jj) * ldc + col] = v;
      }
    }
  }
}

// ---------------- sLSTM pointwise + GroupNorm (block = one (row, head)) ----------------
__global__ __launch_bounds__(256) void pointwise_gn(
    const float* __restrict__ G, const float* __restrict__ c1, const float* __restrict__ n1,
    const float* __restrict__ m1, const float* __restrict__ gnw, const float* __restrict__ gnb,
    float* __restrict__ outc, float* __restrict__ outn, float* __restrict__ outh,
    float* __restrict__ outm, u16* __restrict__ gnbf) {
  int b = blockIdx.x >> 3, h = blockIdx.x & 7, t = threadIdx.x;
  int j = (h << 8) + t;
  size_t rg = (size_t)b * 8192;
  float it = G[rg + j], ft = G[rg + 2048 + j], zt = G[rg + 4096 + j], ot = G[rg + 6144 + j];
  size_t idx = (size_t)b * 2048 + j;
  float cp = c1[idx], np = n1[idx], mp = m1[idx];
  float mt = fmaxf(ft + mp, it);
  float ig = expf(it - mt), fg = expf(ft - mt + mp);
  float zg = tanhf(zt), og = 1.f / (1.f + expf(-ot));
  float ct = fg * cp + ig * zg;
  float nt = fg * np + ig;
  float ht = og * (ct / nt);
  outc[idx] = ct; outn[idx] = nt; outh[idx] = ht; outm[idx] = mt;
  float s = ht, q = ht * ht;
  block_reduce2(s, q);
  float mu = s * (1.f / 256.f);
  float var = q * (1.f / 256.f) - mu * mu;
  float xn = (ht - mu) * rsqrtf(var + 1e-5f);
  gnbf[idx] = f2bf(xn * gnw[j] + gnb[j]);
}

// ---------------- out1 + gelu(out2), zero-pad K to 2752 ----------------
__global__ __launch_bounds__(256) void act_gelu(const float* __restrict__ tmp, u16* __restrict__ gl) {
  int i = blockIdx.x * 256 + threadIdx.x;
  int stride = gridDim.x * 256;
  const int total = 8192 * 2752;
  for (; i < total; i += stride) {
    int b = i / 2752, p = i - b * 2752;
    float y = 0.f;
    if (p < 2730) {
      float x1 = tmp[(size_t)b * 5504 + p];
      float x2 = tmp[(size_t)b * 5504 + 2730 + p];
      y = x1 + x2 * 0.5f * (1.f + erff(x2 * 0.70710678118f));
    }
    gl[(size_t)b * 2752 + p] = f2bf(y);
  }
}

extern "C" void kernel_launch(void* const* d_in, const int* in_sizes, int n_in,
                              void* d_out, int out_size, void* d_ws, size_t ws_size,
                              hipStream_t stream) {
  (void)in_sizes; (void)n_in; (void)out_size; (void)ws_size;
  const float* seq = (const float*)d_in[0];
  const float* c1  = (const float*)d_in[1];
  const float* n1  = (const float*)d_in[2];
  const float* h1  = (const float*)d_in[3];
  const float* m1  = (const float*)d_in[4];
  const float* lnw = (const float*)d_in[5];
  const float* lnb = (const float*)d_in[6];
  const float* gnw = (const float*)d_in[7];
  const float* gnb = (const float*)d_in[8];
  const float* Wi = (const float*)d_in[9];  const float* bi  = (const float*)d_in[10];
  const float* Wf = (const float*)d_in[11]; const float* bf_ = (const float*)d_in[12];
  const float* Wz = (const float*)d_in[13]; const float* bz  = (const float*)d_in[14];
  const float* Wo = (const float*)d_in[15]; const float* bo  = (const float*)d_in[16];
  const float* Ri = (const float*)d_in[17]; const float* Rf = (const float*)d_in[18];
  const float* Rz = (const float*)d_in[19]; const float* Ro = (const float*)d_in[20];
  const float* Wup = (const float*)d_in[21]; const float* bup = (const float*)d_in[22];
  const float* Wdn = (const float*)d_in[23]; const float* bdn = (const float*)d_in[24];

  // ---- workspace layout (peak ~475 MB, with reuse) ----
  size_t off = 0;
  char* base = (char*)d_ws;
  auto alloc = [&](size_t bytes) { char* p = base + off; off += (bytes + 255) & ~(size_t)255; return p; };
  u16*   XBF    = (u16*)  alloc((size_t)B_ROWS * 2048 * 2);
  u16*   HBF    = (u16*)  alloc((size_t)B_ROWS * 2048 * 2);
  u16*   WGT    = (u16*)  alloc((size_t)4 * 2048 * 2048 * 2);   // gate weights, B^T
  u16*   RT     = (u16*)  alloc((size_t)4 * 8 * 256 * 256 * 2); // recurrent, B^T per head
  u16*   WUPT   = (u16*)  alloc((size_t)5632 * 2048 * 2);       // N padded to 22*256
  u16*   WDNT   = (u16*)  alloc((size_t)2048 * 2752 * 2);
  float* BIASG  = (float*)alloc((size_t)8192 * 4);
  float* BIASUP = (float*)alloc((size_t)5504 * 4);
  u16*   GNBF   = (u16*)  alloc((size_t)B_ROWS * 2048 * 2);
  float* G      = (float*)alloc((size_t)B_ROWS * 8192 * 4);
  float* TMP    = G;            // reuse: G dead after pointwise_gn (180 MB <= 268 MB)
  u16*   GL     = WGT;          // reuse: WGT dead after gates GEMM (45 MB <= 67 MB)

  float* OUT  = (float*)d_out;
  float* OUTC = OUT + (size_t)B_ROWS * 2048;
  float* OUTN = OUTC + (size_t)B_ROWS * 2048;
  float* OUTH = OUTN + (size_t)B_ROWS * 2048;
  float* OUTM = OUTH + (size_t)B_ROWS * 2048;

  dim3 tb32(32, 8);

  // 1) LayerNorm -> bf16
  ln_kernel<<<B_ROWS, 256, 0, stream>>>(seq, lnw, lnb, XBF);
  // 2) h_tm1 -> bf16
  cvt_bf16<<<2048, 256, 0, stream>>>(h1, HBF, B_ROWS * 2048);
  // 3) weight transposes -> bf16 B^T layouts
  transpose_cvt<<<dim3(64, 64, 1), tb32, 0, stream>>>(Wi, 0, 2048, 2048, WGT + (size_t)0 * 4194304, 0, 2048);
  transpose_cvt<<<dim3(64, 64, 1), tb32, 0, stream>>>(Wf, 0, 2048, 2048, WGT + (size_t)1 * 4194304, 0, 2048);
  transpose_cvt<<<dim3(64, 64, 1), tb32, 0, stream>>>(Wz, 0, 2048, 2048, WGT + (size_t)2 * 4194304, 0, 2048);
  transpose_cvt<<<dim3(64, 64, 1), tb32, 0, stream>>>(Wo, 0, 2048, 2048, WGT + (size_t)3 * 4194304, 0, 2048);
  transpose_cvt<<<dim3(8, 8, 8), tb32, 0, stream>>>(Ri, 65536, 256, 256, RT + (size_t)0 * 524288, 65536, 256);
  transpose_cvt<<<dim3(8, 8, 8), tb32, 0, stream>>>(Rf, 65536, 256, 256, RT + (size_t)1 * 524288, 65536, 256);
  transpose_cvt<<<dim3(8, 8, 8), tb32, 0, stream>>>(Rz, 65536, 256, 256, RT + (size_t)2 * 524288, 65536, 256);
  transpose_cvt<<<dim3(8, 8, 8), tb32, 0, stream>>>(Ro, 65536, 256, 256, RT + (size_t)3 * 524288, 65536, 256);
  transpose_cvt<<<dim3(171, 64, 1), tb32, 0, stream>>>(Wup, 0, 2048, 5460, WUPT, 0, 2048);
  transpose_cvt<<<dim3(64, 86, 1), tb32, 0, stream>>>(Wdn, 0, 2730, 2048, WDNT, 0, 2752);
  // 4) biases
  pack_bias<<<32, 256, 0, stream>>>(bi, bf_, bz, bo, bup, BIASG, BIASUP);
  // 5) gates GEMM: G[b, g*2048+n] = x@W_g + b_g + h@R_g (block-diag fused as 4 extra K-tiles)
  gemm256<1><<<32 * 32, 512, 0, stream>>>(XBF, 2048, WGT, 2048, 32,
                                          G, 8192, 8192, 32, BIASG, nullptr, 0, HBF, RT);
  // 6) sLSTM pointwise + GroupNorm; writes c,n,h,m states + bf16 activation
  pointwise_gn<<<B_ROWS * 8, 256, 0, stream>>>(G, c1, n1, m1, gnw, gnb,
                                               OUTC, OUTN, OUTH, OUTM, GNBF);
  // 7) up GEMM (N tiles 22 -> 5632, stores guarded at 5460; TMP row stride stays 5504)
  gemm256<0><<<32 * 22, 512, 0, stream>>>(GNBF, 2048, WUPT, 2048, 32,
                                          TMP, 5504, 5460, 22, BIASUP, nullptr, 0, nullptr, nullptr);
  // 8) out1 + gelu(out2) -> bf16 (K padded 2730->2752 with zeros)
  act_gelu<<<8192, 256, 0, stream>>>(TMP, GL);
  // 9) down GEMM + b_dn + seq residual -> out
  gemm256<0><<<32 * 8, 512, 0, stream>>>(GL, 2752, WDNT, 2752, 43,
                                         OUT, 2048, 2048, 8, bdn, seq, 2048, nullptr, nullptr);
}

// Round 6
// 1487.289 us; speedup vs baseline: 1.2533x; 1.0158x over previous
//
#include <hip/hip_runtime.h>
#include <math.h>

typedef unsigned short u16;
typedef __attribute__((ext_vector_type(4))) float f32x4;
typedef __attribute__((ext_vector_type(8))) short bf16x8;
typedef __attribute__((ext_vector_type(8))) unsigned short u16x8;

#define B_ROWS 8192
#define GLDS(gaddr, laddr)                                                                  \
  __builtin_amdgcn_global_load_lds(                                                        \
      (const __attribute__((address_space(1))) unsigned int*)(const void*)(gaddr),          \
      (__attribute__((address_space(3))) unsigned int*)(void*)(laddr), 16, 0, 0)

__device__ __forceinline__ u16 f2bf(float f) {
  unsigned int u = __float_as_uint(f);
  unsigned int r = u + 0x7fffu + ((u >> 16) & 1u);
  return (u16)(r >> 16);
}

// inline-asm LDS read: invisible to LLVM's LDS-DMA alias tracking, so the
// compiler cannot insert its own vmcnt drains before it (rule 18 pattern).
__device__ __forceinline__ bf16x8 dsr(unsigned a) {
  bf16x8 d;
  asm volatile("ds_read_b128 %0, %1" : "=v"(d) : "v"(a));
  return d;
}

// ---------------- block-wide (256 thr) dual reduction ----------------
__device__ __forceinline__ void block_reduce2(float& a, float& b) {
  __shared__ float sb[8];
  #pragma unroll
  for (int off = 32; off > 0; off >>= 1) {
    a += __shfl_down(a, off, 64);
    b += __shfl_down(b, off, 64);
  }
  int lane = threadIdx.x & 63, wid = threadIdx.x >> 6;
  if (lane == 0) { sb[wid] = a; sb[wid + 4] = b; }
  __syncthreads();
  a = sb[0] + sb[1] + sb[2] + sb[3];
  b = sb[4] + sb[5] + sb[6] + sb[7];
  __syncthreads();
}

// ---------------- LayerNorm (2048 cols) -> bf16 ----------------
__global__ __launch_bounds__(256) void ln_kernel(const float* __restrict__ seq,
                                                 const float* __restrict__ w,
                                                 const float* __restrict__ b,
                                                 u16* __restrict__ xbf) {
  int row = blockIdx.x, t = threadIdx.x;
  const f32x4* x = (const f32x4*)(seq + (size_t)row * 2048);
  f32x4 v0 = x[2 * t], v1 = x[2 * t + 1];
  float s = 0.f, q = 0.f;
  #pragma unroll
  for (int i = 0; i < 4; ++i) { s += v0[i] + v1[i]; q += v0[i] * v0[i] + v1[i] * v1[i]; }
  block_reduce2(s, q);
  float mu = s * (1.f / 2048.f);
  float var = q * (1.f / 2048.f) - mu * mu;
  float rstd = rsqrtf(var + 1e-5f);
  f32x4 w0 = ((const f32x4*)w)[2 * t], w1 = ((const f32x4*)w)[2 * t + 1];
  f32x4 b0 = ((const f32x4*)b)[2 * t], b1 = ((const f32x4*)b)[2 * t + 1];
  u16x8 o;
  #pragma unroll
  for (int i = 0; i < 4; ++i) o[i] = f2bf((v0[i] - mu) * rstd * w0[i] + b0[i]);
  #pragma unroll
  for (int i = 0; i < 4; ++i) o[4 + i] = f2bf((v1[i] - mu) * rstd * w1[i] + b1[i]);
  ((u16x8*)(xbf + (size_t)row * 2048))[t] = o;
}

// ---------------- fp32 -> bf16 elementwise ----------------
__global__ __launch_bounds__(256) void cvt_bf16(const float* __restrict__ in,
                                                u16* __restrict__ out, int n) {
  int i = blockIdx.x * 256 + threadIdx.x;
  int stride = gridDim.x * 256;
  for (; i < n; i += stride) out[i] = f2bf(in[i]);
}

// ---------------- transpose + cvt: out[c][r] = bf16(in[r][c]) ----------------
__global__ void transpose_cvt(const float* __restrict__ in, long ibstride, int R, int Cc,
                              u16* __restrict__ out, long obstride, int ldo) {
  in += (size_t)blockIdx.z * ibstride;
  out += (size_t)blockIdx.z * obstride;
  __shared__ float tile[32][33];
  int c0 = blockIdx.x * 32, r0 = blockIdx.y * 32;
  int tx = threadIdx.x, ty = threadIdx.y;
  #pragma unroll
  for (int j = 0; j < 4; ++j) {
    int rr = r0 + ty + j * 8;
    if (rr < R && c0 + tx < Cc) tile[ty + j * 8][tx] = in[(size_t)rr * Cc + c0 + tx];
  }
  __syncthreads();
  #pragma unroll
  for (int j = 0; j < 4; ++j) {
    int cc = c0 + ty + j * 8, rr = r0 + tx;
    if (cc < Cc && rr < R) out[(size_t)cc * ldo + rr] = f2bf(tile[tx][ty + j * 8]);
  }
}

// ---------------- bias packing ----------------
__global__ __launch_bounds__(256) void pack_bias(const float* __restrict__ bi, const float* __restrict__ bf_,
                                                 const float* __restrict__ bz, const float* __restrict__ bo,
                                                 const float* __restrict__ bup,
                                                 float* __restrict__ biasg, float* __restrict__ biasup) {
  int i = blockIdx.x * 256 + threadIdx.x;
  if (i < 8192) {
    int g = i >> 11, j = i & 2047;
    const float* p = (g == 0) ? bi : (g == 1) ? bf_ : (g == 2) ? bz : bo;
    biasg[i] = p[j];
  }
  if (i < 5504) biasup[i] = (i < 5460) ? bup[i] : 0.f;
}

#define MFMA_CLUSTER(lo, AV, BV)                                                           \
  __builtin_amdgcn_s_setprio(1);                                                           \
  _Pragma("unroll")                                                                        \
  for (int mi = 0; mi < 4; ++mi)                                                           \
    _Pragma("unroll")                                                                      \
    for (int ni = 0; ni < 4; ++ni)                                                         \
      acc[(lo) + mi][ni] =                                                                 \
          __builtin_amdgcn_mfma_f32_16x16x32_bf16(AV[mi], BV[ni], acc[(lo) + mi][ni], 0, 0, 0); \
  __builtin_amdgcn_s_setprio(0);

#define WAIT_LGKM(N)                                                                       \
  asm volatile("s_waitcnt lgkmcnt(" #N ")" ::: "memory");                                  \
  __builtin_amdgcn_sched_barrier(0);

// =====================================================================
// 256x256 tile, BK=64, 8-wave (2Mx4N) MFMA GEMM. Deep in-tile read
// pipeline, 2 barriers/tile. Tile-end vmcnt(4)+barrier guarantees ALL of
// tile t landed before tile t starts, so all 24 ds_reads of a tile may
// issue early; counted lgkmcnt per cluster:
//   burst1 (a0,b0,a1 kh0:12) -> stage(t+1,kh1) -> lgkm(4) MFMA1(a0,b0)
//   burst2 (a2,b1 kh1:8)     -> lgkm(8) MFMA2(a1,b0)
//   MID BARRIER (all kh0 reads done) -> stage(t+2,kh0) (kh0 overwrite ok;
//   outstanding reads at barrier are kh1 only) -> burst3 (a3:4)
//   lgkm(4) MFMA3(a2,b1) -> lgkm(0) MFMA4(a3,b1) -> vmcnt(4) -> END BARRIER
// vmcnt ledger (unchanged): 12 outstanding at tile end, drain oldest 8 =
// all 4 halves of t+1; kh0(t+2) stays in flight.
// Bank swizzle s' = s ^ ((row>>1)&3) on global source + LDS read (rule 21).
// =====================================================================
template<int REC>
__global__ __launch_bounds__(512, 2) void gemm256(
    const u16* __restrict__ A, int lda,
    const u16* __restrict__ Bt, int ldb, int KT,
    float* __restrict__ C, long ldc, int Nvalid, int ntN,
    const float* __restrict__ bias,
    const float* __restrict__ addsrc, int ldadd,
    const u16* __restrict__ hbf, const u16* __restrict__ RTw) {
  __shared__ __align__(16) u16 Al[2][2][256][32];
  __shared__ __align__(16) u16 Bl[2][2][256][32];
  const int NT = KT + (REC ? 4 : 0);

  int nb = gridDim.x;
  int bid = blockIdx.x;
  int per = nb >> 3;                       // grids are multiples of 8
  int id = (bid & 7) * per + (bid >> 3);   // XCD-aware swizzle (bijective)
  int m0 = (id / ntN) * 256, n0 = (id % ntN) * 256;

  int tid = threadIdx.x, lane = tid & 63, wave = tid >> 6;
  int wm = wave >> 2, wn = wave & 3;       // 2 x 4 wave grid
  int r = lane & 15, sgrp = lane >> 4;

  const u16* rsrc = nullptr; int hcol = 0;
  if (REC) {
    int g = n0 >> 11, head = (n0 & 2047) >> 8;
    rsrc = RTw + ((size_t)(g * 8 + head)) * 65536;
    hcol = head * 256;
  }

  auto stage = [&](int tt, int which) {    // which: 0=Akh0 1=Akh1 2=Bkh0 3=Bkh1
    if (tt >= NT) return;
    const int isA = (which < 2), kh = which & 1, slot = tt & 1;
    const u16* src; size_t ld;
    if (!REC || tt < KT) {
      if (isA) { src = A + (size_t)m0 * lda + tt * 64; ld = lda; }
      else     { src = Bt + (size_t)n0 * ldb + tt * 64; ld = ldb; }
    } else {
      int t2 = tt - KT;
      if (isA) { src = hbf + (size_t)m0 * 2048 + hcol + t2 * 64; ld = 2048; }
      else     { src = rsrc + t2 * 64; ld = 256; }
    }
    u16* base = isA ? &Al[slot][kh][0][0] : &Bl[slot][kh][0][0];
    #pragma unroll
    for (int c = 0; c < 2; ++c) {
      int R0 = wave * 32 + c * 16;                 // wave-uniform
      int row = R0 + (lane >> 2);
      int s = (lane & 3) ^ ((row >> 1) & 3);       // inverse-swizzled source
      GLDS(src + (size_t)row * ld + kh * 32 + s * 8, base + R0 * 32);
    }
  };

  // 32-bit LDS byte addresses for inline-asm reads
  unsigned AlB = (unsigned)(size_t)(__attribute__((address_space(3))) u16*)&Al[0][0][0][0];
  unsigned BlB = (unsigned)(size_t)(__attribute__((address_space(3))) u16*)&Bl[0][0][0][0];
  int sA = sgrp ^ ((r >> 1) & 3);                  // row&15 == r for all frag rows
  unsigned aBaseT = AlB + (unsigned)((wm * 128 + r) * 64 + sA * 16);
  unsigned bBaseT = BlB + (unsigned)((wn * 64 + r) * 64 + sA * 16);

  f32x4 acc[8][4] = {};
  bf16x8 a0[4], a1[4], a2[4], a3[4], b0[4], b1[4];

  // ---- prologue: tile0 (4 halves) + tile1 {Akh0,Bkh0} ----
  stage(0, 0); stage(0, 2); stage(0, 1); stage(0, 3);
  stage(1, 0); stage(1, 2);
  asm volatile("s_waitcnt vmcnt(4)" ::: "memory");
  __builtin_amdgcn_s_barrier();

  for (int t = 0; t < NT; ++t) {
    unsigned sl = (unsigned)(t & 1) * 32768u;
    unsigned ab = aBaseT + sl, bb = bBaseT + sl;
    __builtin_amdgcn_sched_barrier(0);
    // ---- burst1: all kh0 reads (12) ----
    a0[0] = dsr(ab);          a0[1] = dsr(ab + 1024);
    a0[2] = dsr(ab + 2048);   a0[3] = dsr(ab + 3072);
    b0[0] = dsr(bb);          b0[1] = dsr(bb + 1024);
    b0[2] = dsr(bb + 2048);   b0[3] = dsr(bb + 3072);
    a1[0] = dsr(ab + 4096);   a1[1] = dsr(ab + 5120);
    a1[2] = dsr(ab + 6144);   a1[3] = dsr(ab + 7168);
    // stage next tile's kh1 halves (-> slot^1, disjoint from all reads)
    stage(t + 1, 1); stage(t + 1, 3);
    // ---- cluster1: a0 x b0 ----
    WAIT_LGKM(4);
    MFMA_CLUSTER(0, a0, b0);
    // ---- burst2: kh1 reads a2,b1 (8) ----
    a2[0] = dsr(ab + 16384);  a2[1] = dsr(ab + 17408);
    a2[2] = dsr(ab + 18432);  a2[3] = dsr(ab + 19456);
    b1[0] = dsr(bb + 16384);  b1[1] = dsr(bb + 17408);
    b1[2] = dsr(bb + 18432);  b1[3] = dsr(bb + 19456);
    // ---- cluster2: a1 x b0 ----
    WAIT_LGKM(8);
    MFMA_CLUSTER(4, a1, b0);
    __builtin_amdgcn_s_barrier();            // all waves' kh0 reads complete
    __builtin_amdgcn_sched_barrier(0);
    // safe to overwrite kh0 of current slot (outstanding reads are kh1 only)
    stage(t + 2, 0); stage(t + 2, 2);
    // ---- burst3: a3 (4) ----
    a3[0] = dsr(ab + 20480);  a3[1] = dsr(ab + 21504);
    a3[2] = dsr(ab + 22528);  a3[3] = dsr(ab + 23552);
    // ---- cluster3: a2 x b1 ----
    WAIT_LGKM(4);
    MFMA_CLUSTER(0, a2, b1);
    // ---- cluster4: a3 x b1 ----
    WAIT_LGKM(0);
    MFMA_CLUSTER(4, a3, b1);
    if (t + 2 < NT)      { asm volatile("s_waitcnt vmcnt(4)" ::: "memory"); }
    else if (t + 1 < NT) { asm volatile("s_waitcnt vmcnt(0)" ::: "memory"); }
    __builtin_amdgcn_s_barrier();
  }

  // ---- epilogue ----
  #pragma unroll
  for (int a = 0; a < 8; ++a) {
    int row0 = m0 + wm * 128 + a * 16 + sgrp * 4;
    #pragma unroll
    for (int ni = 0; ni < 4; ++ni) {
      int col = n0 + wn * 64 + ni * 16 + r;
      if (col >= Nvalid) continue;
      float bv = bias ? bias[col] : 0.f;
      #pragma unroll
      for (int jj = 0; jj < 4; ++jj) {
        float v = acc[a][ni][jj] + bv;
        if (addsrc) v += addsrc[(size_t)(row0 + jj) * ldadd + col];
        C[(size_t)(row0 + jj) * ldc + col] = v;
      }
    }
  }
}

// ---------------- sLSTM pointwise + GroupNorm (block = one (row, head)) ----------------
__global__ __launch_bounds__(256) void pointwise_gn(
    const float* __restrict__ G, const float* __restrict__ c1, const float* __restrict__ n1,
    const float* __restrict__ m1, const float* __restrict__ gnw, const float* __restrict__ gnb,
    float* __restrict__ outc, float* __restrict__ outn, float* __restrict__ outh,
    float* __restrict__ outm, u16* __restrict__ gnbf) {
  int b = blockIdx.x >> 3, h = blockIdx.x & 7, t = threadIdx.x;
  int j = (h << 8) + t;
  size_t rg = (size_t)b * 8192;
  float it = G[rg + j], ft = G[rg + 2048 + j], zt = G[rg + 4096 + j], ot = G[rg + 6144 + j];
  size_t idx = (size_t)b * 2048 + j;
  float cp = c1[idx], np = n1[idx], mp = m1[idx];
  float mt = fmaxf(ft + mp, it);
  float ig = expf(it - mt), fg = expf(ft - mt + mp);
  float zg = tanhf(zt), og = 1.f / (1.f + expf(-ot));
  float ct = fg * cp + ig * zg;
  float nt = fg * np + ig;
  float ht = og * (ct / nt);
  outc[idx] = ct; outn[idx] = nt; outh[idx] = ht; outm[idx] = mt;
  float s = ht, q = ht * ht;
  block_reduce2(s, q);
  float mu = s * (1.f / 256.f);
  float var = q * (1.f / 256.f) - mu * mu;
  float xn = (ht - mu) * rsqrtf(var + 1e-5f);
  gnbf[idx] = f2bf(xn * gnw[j] + gnb[j]);
}

// ---------------- out1 + gelu(out2), zero-pad K to 2752 (block = row) ----------------
__global__ __launch_bounds__(256) void act_gelu(const float* __restrict__ tmp, u16* __restrict__ gl) {
  int b = blockIdx.x;
  const float* row = tmp + (size_t)b * 5504;
  u16* orow = gl + (size_t)b * 2752;
  for (int p = threadIdx.x; p < 2752; p += 256) {
    float y = 0.f;
    if (p < 2730) {
      float x1 = row[p], x2 = row[2730 + p];
      y = x1 + x2 * 0.5f * (1.f + erff(x2 * 0.70710678118f));
    }
    orow[p] = f2bf(y);
  }
}

extern "C" void kernel_launch(void* const* d_in, const int* in_sizes, int n_in,
                              void* d_out, int out_size, void* d_ws, size_t ws_size,
                              hipStream_t stream) {
  (void)in_sizes; (void)n_in; (void)out_size; (void)ws_size;
  const float* seq = (const float*)d_in[0];
  const float* c1  = (const float*)d_in[1];
  const float* n1  = (const float*)d_in[2];
  const float* h1  = (const float*)d_in[3];
  const float* m1  = (const float*)d_in[4];
  const float* lnw = (const float*)d_in[5];
  const float* lnb = (const float*)d_in[6];
  const float* gnw = (const float*)d_in[7];
  const float* gnb = (const float*)d_in[8];
  const float* Wi = (const float*)d_in[9];  const float* bi  = (const float*)d_in[10];
  const float* Wf = (const float*)d_in[11]; const float* bf_ = (const float*)d_in[12];
  const float* Wz = (const float*)d_in[13]; const float* bz  = (const float*)d_in[14];
  const float* Wo = (const float*)d_in[15]; const float* bo  = (const float*)d_in[16];
  const float* Ri = (const float*)d_in[17]; const float* Rf = (const float*)d_in[18];
  const float* Rz = (const float*)d_in[19]; const float* Ro = (const float*)d_in[20];
  const float* Wup = (const float*)d_in[21]; const float* bup = (const float*)d_in[22];
  const float* Wdn = (const float*)d_in[23]; const float* bdn = (const float*)d_in[24];

  // ---- workspace layout (peak ~475 MB, with reuse) ----
  size_t off = 0;
  char* base = (char*)d_ws;
  auto alloc = [&](size_t bytes) { char* p = base + off; off += (bytes + 255) & ~(size_t)255; return p; };
  u16*   XBF    = (u16*)  alloc((size_t)B_ROWS * 2048 * 2);
  u16*   HBF    = (u16*)  alloc((size_t)B_ROWS * 2048 * 2);
  u16*   WGT    = (u16*)  alloc((size_t)4 * 2048 * 2048 * 2);   // gate weights, B^T
  u16*   RT     = (u16*)  alloc((size_t)4 * 8 * 256 * 256 * 2); // recurrent, B^T per head
  u16*   WUPT   = (u16*)  alloc((size_t)5632 * 2048 * 2);       // N padded to 22*256
  u16*   WDNT   = (u16*)  alloc((size_t)2048 * 2752 * 2);
  float* BIASG  = (float*)alloc((size_t)8192 * 4);
  float* BIASUP = (float*)alloc((size_t)5504 * 4);
  u16*   GNBF   = (u16*)  alloc((size_t)B_ROWS * 2048 * 2);
  float* G      = (float*)alloc((size_t)B_ROWS * 8192 * 4);
  float* TMP    = G;            // reuse: G dead after pointwise_gn (180 MB <= 268 MB)
  u16*   GL     = WGT;          // reuse: WGT dead after gates GEMM (45 MB <= 67 MB)

  float* OUT  = (float*)d_out;
  float* OUTC = OUT + (size_t)B_ROWS * 2048;
  float* OUTN = OUTC + (size_t)B_ROWS * 2048;
  float* OUTH = OUTN + (size_t)B_ROWS * 2048;
  float* OUTM = OUTH + (size_t)B_ROWS * 2048;

  dim3 tb32(32, 8);

  // 1) LayerNorm -> bf16
  ln_kernel<<<B_ROWS, 256, 0, stream>>>(seq, lnw, lnb, XBF);
  // 2) h_tm1 -> bf16
  cvt_bf16<<<2048, 256, 0, stream>>>(h1, HBF, B_ROWS * 2048);
  // 3) weight transposes -> bf16 B^T layouts
  transpose_cvt<<<dim3(64, 64, 1), tb32, 0, stream>>>(Wi, 0, 2048, 2048, WGT + (size_t)0 * 4194304, 0, 2048);
  transpose_cvt<<<dim3(64, 64, 1), tb32, 0, stream>>>(Wf, 0, 2048, 2048, WGT + (size_t)1 * 4194304, 0, 2048);
  transpose_cvt<<<dim3(64, 64, 1), tb32, 0, stream>>>(Wz, 0, 2048, 2048, WGT + (size_t)2 * 4194304, 0, 2048);
  transpose_cvt<<<dim3(64, 64, 1), tb32, 0, stream>>>(Wo, 0, 2048, 2048, WGT + (size_t)3 * 4194304, 0, 2048);
  transpose_cvt<<<dim3(8, 8, 8), tb32, 0, stream>>>(Ri, 65536, 256, 256, RT + (size_t)0 * 524288, 65536, 256);
  transpose_cvt<<<dim3(8, 8, 8), tb32, 0, stream>>>(Rf, 65536, 256, 256, RT + (size_t)1 * 524288, 65536, 256);
  transpose_cvt<<<dim3(8, 8, 8), tb32, 0, stream>>>(Rz, 65536, 256, 256, RT + (size_t)2 * 524288, 65536, 256);
  transpose_cvt<<<dim3(8, 8, 8), tb32, 0, stream>>>(Ro, 65536, 256, 256, RT + (size_t)3 * 524288, 65536, 256);
  transpose_cvt<<<dim3(171, 64, 1), tb32, 0, stream>>>(Wup, 0, 2048, 5460, WUPT, 0, 2048);
  transpose_cvt<<<dim3(64, 86, 1), tb32, 0, stream>>>(Wdn, 0, 2730, 2048, WDNT, 0, 2752);
  // 4) biases
  pack_bias<<<32, 256, 0, stream>>>(bi, bf_, bz, bo, bup, BIASG, BIASUP);
  // 5) gates GEMM: G[b, g*2048+n] = x@W_g + b_g + h@R_g (block-diag fused as 4 extra K-tiles)
  gemm256<1><<<32 * 32, 512, 0, stream>>>(XBF, 2048, WGT, 2048, 32,
                                          G, 8192, 8192, 32, BIASG, nullptr, 0, HBF, RT);
  // 6) sLSTM pointwise + GroupNorm; writes c,n,h,m states + bf16 activation
  pointwise_gn<<<B_ROWS * 8, 256, 0, stream>>>(G, c1, n1, m1, gnw, gnb,
                                               OUTC, OUTN, OUTH, OUTM, GNBF);
  // 7) up GEMM (N tiles 22 -> 5632, stores guarded at 5460; TMP row stride stays 5504)
  gemm256<0><<<32 * 22, 512, 0, stream>>>(GNBF, 2048, WUPT, 2048, 32,
                                          TMP, 5504, 5460, 22, BIASUP, nullptr, 0, nullptr, nullptr);
  // 8) out1 + gelu(out2) -> bf16 (K padded 2730->2752 with zeros)
  act_gelu<<<8192, 256, 0, stream>>>(TMP, GL);
  // 9) down GEMM + b_dn + seq residual -> out
  gemm256<0><<<32 * 8, 512, 0, stream>>>(GL, 2752, WDNT, 2752, 43,
                                         OUT, 2048, 2048, 8, bdn, seq, 2048, nullptr, nullptr);
}